// Round 1
// baseline (1196.890 us; speedup 1.0000x reference)
//
#include <hip/hip_runtime.h>

// MPNN, 3 layers, N=50000, E=800000, D=64, fp32.
// Per layer: h[dst] += x[src] (scatter), then
// out = relu((h+x)@W1 + x@W2 + bu + (deg+1)*dvec),
// where W1 = Wm @ Wu_top (precomputed), W2 = Wu_bot, dvec = bm @ Wu_top.

#define DIM 64

__global__ __launch_bounds__(256) void fuse_weights_kernel(
    const float* __restrict__ Wm, const float* __restrict__ bm,
    const float* __restrict__ Wu, float* __restrict__ W1,
    float* __restrict__ dv) {
  __shared__ float sWm[64 * 64];
  __shared__ float sWu[64 * 64];  // top half of Wu (rows 0..63)
  const int tid = threadIdx.x;
  for (int i = tid; i < 4096; i += 256) {
    sWm[i] = Wm[i];
    sWu[i] = Wu[i];
  }
  __syncthreads();
  for (int i = tid; i < 4096; i += 256) {
    const int r = i >> 6, c = i & 63;
    float acc = 0.f;
#pragma unroll
    for (int k = 0; k < 64; ++k) acc = fmaf(sWm[r * 64 + k], sWu[k * 64 + c], acc);
    W1[i] = acc;
  }
  if (tid < 64) {
    float acc = 0.f;
#pragma unroll
    for (int k = 0; k < 64; ++k) acc = fmaf(bm[k], sWu[k * 64 + tid], acc);
    dv[tid] = acc;
  }
}

__global__ __launch_bounds__(256) void deg_kernel(const int* __restrict__ dst,
                                                  int* __restrict__ deg, int E) {
  const int e = blockIdx.x * 256 + threadIdx.x;
  if (e < E) atomicAdd(&deg[dst[e]], 1);
}

__global__ __launch_bounds__(256) void scatter_kernel(
    const float* __restrict__ xin, const int* __restrict__ src,
    const int* __restrict__ dst, float* __restrict__ h, int E) {
  const int gid = blockIdx.x * 256 + threadIdx.x;
  const int stride = gridDim.x * 256;
  const int lane = threadIdx.x & 63;
  const int total = E * 64;
  for (int t = gid; t < total; t += stride) {
    const int e = t >> 6;  // uniform across the wave (stride % 64 == 0)
    const int s = src[e];
    const int d = dst[e];
    atomicAdd(&h[d * 64 + lane], xin[s * 64 + lane]);
  }
}

__global__ __launch_bounds__(256) void update_kernel(
    const float* __restrict__ h, const float* __restrict__ xin,
    const float* __restrict__ W1, const float* __restrict__ Wu,
    const float* __restrict__ bu, const float* __restrict__ dvec,
    const int* __restrict__ deg, float* __restrict__ out, int n) {
  __shared__ float sW1[64 * 64];
  __shared__ float sW2[64 * 64];
  __shared__ float sb[64];
  __shared__ float sd[64];
  __shared__ float shx[16][64];  // h + x rows
  __shared__ float sx[16][64];   // x rows
  const int tid = threadIdx.x;
  for (int i = tid; i < 4096; i += 256) {
    sW1[i] = W1[i];
    sW2[i] = Wu[4096 + i];  // bottom half of Wu (rows 64..127)
  }
  if (tid < 64) {
    sb[tid] = bu[tid];
    sd[tid] = dvec[tid];
  }
  __syncthreads();
  const int w = tid >> 6;     // wave id 0..3
  const int lane = tid & 63;  // output column
  for (int base = blockIdx.x * 16; base < n; base += gridDim.x * 16) {
    // Each wave stages its own 4 rows (intra-wave LDS use only).
#pragma unroll
    for (int r = 0; r < 4; ++r) {
      const int row = base + w * 4 + r;
      float xv = 0.f, hv = 0.f;
      if (row < n) {
        xv = xin[(size_t)row * 64 + lane];
        hv = h[(size_t)row * 64 + lane];
      }
      shx[w * 4 + r][lane] = hv + xv;
      sx[w * 4 + r][lane] = xv;
    }
    __builtin_amdgcn_wave_barrier();  // fence compiler reordering; intra-wave DS is in-order
    float acc0 = 0.f, acc1 = 0.f, acc2 = 0.f, acc3 = 0.f;
    const float4* hx0 = (const float4*)shx[w * 4 + 0];
    const float4* hx1 = (const float4*)shx[w * 4 + 1];
    const float4* hx2 = (const float4*)shx[w * 4 + 2];
    const float4* hx3 = (const float4*)shx[w * 4 + 3];
    const float4* xr0 = (const float4*)sx[w * 4 + 0];
    const float4* xr1 = (const float4*)sx[w * 4 + 1];
    const float4* xr2 = (const float4*)sx[w * 4 + 2];
    const float4* xr3 = (const float4*)sx[w * 4 + 3];
#pragma unroll
    for (int kq = 0; kq < 16; ++kq) {
      const float4 a0 = hx0[kq], a1 = hx1[kq], a2 = hx2[kq], a3 = hx3[kq];
      const float4 b0 = xr0[kq], b1 = xr1[kq], b2 = xr2[kq], b3 = xr3[kq];
      const float* pa0 = (const float*)&a0;
      const float* pa1 = (const float*)&a1;
      const float* pa2 = (const float*)&a2;
      const float* pa3 = (const float*)&a3;
      const float* pb0 = (const float*)&b0;
      const float* pb1 = (const float*)&b1;
      const float* pb2 = (const float*)&b2;
      const float* pb3 = (const float*)&b3;
#pragma unroll
      for (int j = 0; j < 4; ++j) {
        const int k = kq * 4 + j;
        const float w1 = sW1[k * 64 + lane];
        const float w2 = sW2[k * 64 + lane];
        acc0 = fmaf(pa0[j], w1, fmaf(pb0[j], w2, acc0));
        acc1 = fmaf(pa1[j], w1, fmaf(pb1[j], w2, acc1));
        acc2 = fmaf(pa2[j], w1, fmaf(pb2[j], w2, acc2));
        acc3 = fmaf(pa3[j], w1, fmaf(pb3[j], w2, acc3));
      }
    }
#pragma unroll
    for (int r = 0; r < 4; ++r) {
      const int row = base + w * 4 + r;
      if (row < n) {
        const float a = (r == 0) ? acc0 : (r == 1) ? acc1 : (r == 2) ? acc2 : acc3;
        const float degf = (float)(deg[row] + 1);
        const float v = a + sb[lane] + degf * sd[lane];
        out[(size_t)row * 64 + lane] = v > 0.f ? v : 0.f;
      }
    }
    __builtin_amdgcn_wave_barrier();
  }
}

extern "C" void kernel_launch(void* const* d_in, const int* in_sizes, int n_in,
                              void* d_out, int out_size, void* d_ws, size_t ws_size,
                              hipStream_t stream) {
  const float* x = (const float*)d_in[0];
  const int* ei = (const int*)d_in[1];
  const int n = in_sizes[0] / DIM;   // 50000
  const int E = in_sizes[1] / 2;     // 800000
  const int* srcp = ei;
  const int* dstp = ei + E;

  // Workspace layout (floats):
  float* ws = (float*)d_ws;
  float* h = ws;                              // n*64
  float* y1 = h + (size_t)n * DIM;            // n*64 (layer-1 output)
  int* deg = (int*)(y1 + (size_t)n * DIM);    // n ints
  float* W1 = (float*)(deg + n);              // 3*4096
  float* dv = W1 + 3 * 4096;                  // 3*64

  // Precompute fused weights per layer.
  for (int l = 0; l < 3; ++l) {
    const float* Wm = (const float*)d_in[2 + 4 * l];
    const float* bm = (const float*)d_in[3 + 4 * l];
    const float* Wu = (const float*)d_in[4 + 4 * l];
    fuse_weights_kernel<<<1, 256, 0, stream>>>(Wm, bm, Wu, W1 + l * 4096, dv + l * 64);
  }

  // In-degree (excluding self-loop; update adds +1).
  hipMemsetAsync(deg, 0, (size_t)n * sizeof(int), stream);
  deg_kernel<<<(E + 255) / 256, 256, 0, stream>>>(dstp, deg, E);

  // Layer chain: x -> d_out -> y1 -> d_out
  float* outs[3] = {(float*)d_out, y1, (float*)d_out};
  const float* xin = x;
  for (int l = 0; l < 3; ++l) {
    hipMemsetAsync(h, 0, (size_t)n * DIM * sizeof(float), stream);
    scatter_kernel<<<8192, 256, 0, stream>>>(xin, srcp, dstp, h, E);
    update_kernel<<<2048, 256, 0, stream>>>(
        h, xin, W1 + l * 4096, (const float*)d_in[4 + 4 * l],
        (const float*)d_in[5 + 4 * l], dv + l * 64, deg, outs[l], n);
    xin = outs[l];
  }
}

// Round 2
// 967.376 us; speedup vs baseline: 1.2373x; 1.2373x over previous
//
#include <hip/hip_runtime.h>

// MPNN, 3 layers, N=50000, E=800000, D=64, fp32.
// Algebra per layer:
//   hx[d]  = x[d] + sum_{e: dst=d} x[src_e]           (gather via CSR, no atomics)
//   out    = relu(hx@W1 + x@W2 + bu + (deg+1)*dvec)
//   W1 = Wm @ Wu_top, W2 = Wu_bot, dvec = bm @ Wu_top (precomputed once)

#define DIM 64

__global__ __launch_bounds__(256) void fuse_weights_kernel(
    const float* __restrict__ Wm0, const float* __restrict__ bm0, const float* __restrict__ Wu0,
    const float* __restrict__ Wm1, const float* __restrict__ bm1, const float* __restrict__ Wu1,
    const float* __restrict__ Wm2, const float* __restrict__ bm2, const float* __restrict__ Wu2,
    float* __restrict__ W1, float* __restrict__ dv) {
  const int l = blockIdx.x;
  const float* Wm = l == 0 ? Wm0 : l == 1 ? Wm1 : Wm2;
  const float* bm = l == 0 ? bm0 : l == 1 ? bm1 : bm2;
  const float* Wu = l == 0 ? Wu0 : l == 1 ? Wu1 : Wu2;
  float* W1l = W1 + l * 4096;
  float* dvl = dv + l * 64;
  __shared__ float sWm[64 * 64];
  __shared__ float sWu[64 * 64];  // top half of Wu (rows 0..63)
  const int tid = threadIdx.x;
  for (int i = tid; i < 4096; i += 256) {
    sWm[i] = Wm[i];
    sWu[i] = Wu[i];
  }
  __syncthreads();
  for (int i = tid; i < 4096; i += 256) {
    const int r = i >> 6, c = i & 63;
    float acc = 0.f;
#pragma unroll
    for (int k = 0; k < 64; ++k) acc = fmaf(sWm[r * 64 + k], sWu[k * 64 + c], acc);
    W1l[i] = acc;
  }
  if (tid < 64) {
    float acc = 0.f;
#pragma unroll
    for (int k = 0; k < 64; ++k) acc = fmaf(bm[k], sWu[k * 64 + tid], acc);
    dvl[tid] = acc;
  }
}

__global__ __launch_bounds__(256) void deg_kernel(const int* __restrict__ dst,
                                                  int* __restrict__ deg, int E) {
  const int e = blockIdx.x * 256 + threadIdx.x;
  if (e < E) atomicAdd(&deg[dst[e]], 1);
}

__global__ __launch_bounds__(1024) void scan_kernel(const int* __restrict__ deg,
                                                    int* __restrict__ rowptr, int n) {
  __shared__ int part[1024];
  const int t = threadIdx.x;
  const int chunk = (n + 1023) / 1024;
  const int b = t * chunk;
  const int e = min(n, b + chunk);
  int s = 0;
  for (int i = b; i < e; ++i) s += deg[i];
  part[t] = s;
  __syncthreads();
  for (int off = 1; off < 1024; off <<= 1) {
    int v = (t >= off) ? part[t - off] : 0;
    __syncthreads();
    part[t] += v;
    __syncthreads();
  }
  int run = (t == 0) ? 0 : part[t - 1];
  for (int i = b; i < e; ++i) {
    rowptr[i] = run;
    run += deg[i];
  }
  if (t == 1023) rowptr[n] = part[1023];
}

__global__ __launch_bounds__(256) void fill_kernel(
    const int* __restrict__ src, const int* __restrict__ dst,
    const int* __restrict__ rowptr, int* __restrict__ cursor,
    int* __restrict__ csr_src, int E) {
  const int e = blockIdx.x * 256 + threadIdx.x;
  if (e < E) {
    const int d = dst[e];
    const int p = atomicAdd(&cursor[d], 1);
    csr_src[rowptr[d] + p] = src[e];
  }
}

// One wave per node: hx[d] = x[d] + sum_{incoming} x[s]
__global__ __launch_bounds__(256) void aggregate_kernel(
    const float* __restrict__ x, const int* __restrict__ rowptr,
    const int* __restrict__ csr_src, float* __restrict__ hx, int n) {
  const int wid = (blockIdx.x * 256 + threadIdx.x) >> 6;
  const int lane = threadIdx.x & 63;
  if (wid >= n) return;
  const int beg = rowptr[wid];
  const int end = rowptr[wid + 1];
  float acc = x[(size_t)wid * 64 + lane];
  int s_next = (beg < end) ? csr_src[beg] : 0;
  for (int i = beg; i < end; ++i) {
    const int s = s_next;
    if (i + 1 < end) s_next = csr_src[i + 1];
    acc += x[(size_t)s * 64 + lane];
  }
  hx[(size_t)wid * 64 + lane] = acc;
}

__global__ __launch_bounds__(256) void update_kernel(
    const float* __restrict__ hx, const float* __restrict__ xin,
    const float* __restrict__ W1, const float* __restrict__ Wu,
    const float* __restrict__ bu, const float* __restrict__ dvec,
    const int* __restrict__ deg, float* __restrict__ out, int n) {
  __shared__ float sW1[64 * 64];
  __shared__ float sW2[64 * 64];
  __shared__ float sb[64];
  __shared__ float sd[64];
  __shared__ float shx[16][64];  // hx rows (already include self-loop x)
  __shared__ float sx[16][64];   // x rows
  const int tid = threadIdx.x;
  for (int i = tid; i < 4096; i += 256) {
    sW1[i] = W1[i];
    sW2[i] = Wu[4096 + i];  // bottom half of Wu (rows 64..127)
  }
  if (tid < 64) {
    sb[tid] = bu[tid];
    sd[tid] = dvec[tid];
  }
  __syncthreads();
  const int w = tid >> 6;
  const int lane = tid & 63;
  const int w4 = w * 4;
  for (int base = blockIdx.x * 16; base < n; base += gridDim.x * 16) {
#pragma unroll
    for (int r = 0; r < 4; ++r) {
      const int row = base + w4 + r;
      float xv = 0.f, hv = 0.f;
      if (row < n) {
        xv = xin[(size_t)row * 64 + lane];
        hv = hx[(size_t)row * 64 + lane];
      }
      shx[w4 + r][lane] = hv;
      sx[w4 + r][lane] = xv;
    }
    __builtin_amdgcn_wave_barrier();  // intra-wave LDS only; fence compiler reordering
    float acc0 = 0.f, acc1 = 0.f, acc2 = 0.f, acc3 = 0.f;
    const float4* phx0 = (const float4*)shx[w4 + 0];
    const float4* phx1 = (const float4*)shx[w4 + 1];
    const float4* phx2 = (const float4*)shx[w4 + 2];
    const float4* phx3 = (const float4*)shx[w4 + 3];
    const float4* px0 = (const float4*)sx[w4 + 0];
    const float4* px1 = (const float4*)sx[w4 + 1];
    const float4* px2 = (const float4*)sx[w4 + 2];
    const float4* px3 = (const float4*)sx[w4 + 3];
#pragma unroll
    for (int kq = 0; kq < 16; ++kq) {
      const float4 a0 = phx0[kq], a1 = phx1[kq], a2 = phx2[kq], a3 = phx3[kq];
      const float4 b0 = px0[kq], b1 = px1[kq], b2 = px2[kq], b3 = px3[kq];
      const int k0 = kq * 4;
      float w1, w2;
      w1 = sW1[(k0 + 0) * 64 + lane];
      w2 = sW2[(k0 + 0) * 64 + lane];
      acc0 = fmaf(a0.x, w1, fmaf(b0.x, w2, acc0));
      acc1 = fmaf(a1.x, w1, fmaf(b1.x, w2, acc1));
      acc2 = fmaf(a2.x, w1, fmaf(b2.x, w2, acc2));
      acc3 = fmaf(a3.x, w1, fmaf(b3.x, w2, acc3));
      w1 = sW1[(k0 + 1) * 64 + lane];
      w2 = sW2[(k0 + 1) * 64 + lane];
      acc0 = fmaf(a0.y, w1, fmaf(b0.y, w2, acc0));
      acc1 = fmaf(a1.y, w1, fmaf(b1.y, w2, acc1));
      acc2 = fmaf(a2.y, w1, fmaf(b2.y, w2, acc2));
      acc3 = fmaf(a3.y, w1, fmaf(b3.y, w2, acc3));
      w1 = sW1[(k0 + 2) * 64 + lane];
      w2 = sW2[(k0 + 2) * 64 + lane];
      acc0 = fmaf(a0.z, w1, fmaf(b0.z, w2, acc0));
      acc1 = fmaf(a1.z, w1, fmaf(b1.z, w2, acc1));
      acc2 = fmaf(a2.z, w1, fmaf(b2.z, w2, acc2));
      acc3 = fmaf(a3.z, w1, fmaf(b3.z, w2, acc3));
      w1 = sW1[(k0 + 3) * 64 + lane];
      w2 = sW2[(k0 + 3) * 64 + lane];
      acc0 = fmaf(a0.w, w1, fmaf(b0.w, w2, acc0));
      acc1 = fmaf(a1.w, w1, fmaf(b1.w, w2, acc1));
      acc2 = fmaf(a2.w, w1, fmaf(b2.w, w2, acc2));
      acc3 = fmaf(a3.w, w1, fmaf(b3.w, w2, acc3));
    }
#pragma unroll
    for (int r = 0; r < 4; ++r) {
      const int row = base + w4 + r;
      if (row < n) {
        const float a = (r == 0) ? acc0 : (r == 1) ? acc1 : (r == 2) ? acc2 : acc3;
        const float degf = (float)(deg[row] + 1);
        const float v = a + sb[lane] + degf * sd[lane];
        out[(size_t)row * 64 + lane] = v > 0.f ? v : 0.f;
      }
    }
    __builtin_amdgcn_wave_barrier();
  }
}

extern "C" void kernel_launch(void* const* d_in, const int* in_sizes, int n_in,
                              void* d_out, int out_size, void* d_ws, size_t ws_size,
                              hipStream_t stream) {
  const float* x = (const float*)d_in[0];
  const int* ei = (const int*)d_in[1];
  const int n = in_sizes[0] / DIM;   // 50000
  const int E = in_sizes[1] / 2;     // 800000
  const int* srcp = ei;
  const int* dstp = ei + E;

  // Workspace layout:
  float* hx = (float*)d_ws;                    // n*64 floats (12.8 MB)
  float* y1 = hx + (size_t)n * DIM;            // n*64 floats (12.8 MB)
  int* deg = (int*)(y1 + (size_t)n * DIM);     // n
  int* rowptr = deg + n;                       // n+1
  int* cursor = rowptr + n + 1;                // n
  int* csr_src = cursor + n;                   // E (3.2 MB)
  float* W1 = (float*)(csr_src + E);           // 3*4096
  float* dv = W1 + 3 * 4096;                   // 3*64

  // One-time prep: fused weights + CSR build.
  fuse_weights_kernel<<<3, 256, 0, stream>>>(
      (const float*)d_in[2], (const float*)d_in[3], (const float*)d_in[4],
      (const float*)d_in[6], (const float*)d_in[7], (const float*)d_in[8],
      (const float*)d_in[10], (const float*)d_in[11], (const float*)d_in[12],
      W1, dv);
  hipMemsetAsync(deg, 0, (size_t)n * sizeof(int), stream);
  hipMemsetAsync(cursor, 0, (size_t)n * sizeof(int), stream);
  deg_kernel<<<(E + 255) / 256, 256, 0, stream>>>(dstp, deg, E);
  scan_kernel<<<1, 1024, 0, stream>>>(deg, rowptr, n);
  fill_kernel<<<(E + 255) / 256, 256, 0, stream>>>(srcp, dstp, rowptr, cursor, csr_src, E);

  // Layer chain: x -> d_out -> y1 -> d_out
  float* outs[3] = {(float*)d_out, y1, (float*)d_out};
  const float* xin = x;
  const int agg_blocks = (n * 64 + 255) / 256;   // one wave per node
  const int upd_blocks = (n + 15) / 16;
  for (int l = 0; l < 3; ++l) {
    aggregate_kernel<<<agg_blocks, 256, 0, stream>>>(xin, rowptr, csr_src, hx, n);
    update_kernel<<<upd_blocks, 256, 0, stream>>>(
        hx, xin, W1 + l * 4096, (const float*)d_in[4 + 4 * l],
        (const float*)d_in[5 + 4 * l], dv + l * 64, deg, outs[l], n);
    xin = outs[l];
  }
}

// Round 3
// 426.434 us; speedup vs baseline: 2.8067x; 2.2685x over previous
//
#include <hip/hip_runtime.h>

// MPNN, 3 layers, N=50000, E=800000, D=64, fp32.
// Per layer (fused into ONE kernel, one wave per node):
//   hv   = x[d] + sum_{e: dst=d} x[src_e]          (CSR gather, registers only)
//   out  = relu(hv@W1 + x[d]@W2 + bu + (deg+1)*dvec)
// W1 = Wm @ Wu_top, W2 = Wu_bot, dvec = bm @ Wu_top (precomputed once).
// GEMM rows are done with register-resident weight columns (lane = output col)
// and v_readlane broadcasts of hv/xv -- no LDS, no barriers, no spill.

#define DIM 64

__global__ __launch_bounds__(256) void fuse_weights_kernel(
    const float* __restrict__ Wm0, const float* __restrict__ bm0, const float* __restrict__ Wu0,
    const float* __restrict__ Wm1, const float* __restrict__ bm1, const float* __restrict__ Wu1,
    const float* __restrict__ Wm2, const float* __restrict__ bm2, const float* __restrict__ Wu2,
    float* __restrict__ W1, float* __restrict__ dv) {
  const int l = blockIdx.x;
  const float* Wm = l == 0 ? Wm0 : l == 1 ? Wm1 : Wm2;
  const float* bm = l == 0 ? bm0 : l == 1 ? bm1 : bm2;
  const float* Wu = l == 0 ? Wu0 : l == 1 ? Wu1 : Wu2;
  float* W1l = W1 + l * 4096;
  float* dvl = dv + l * 64;
  __shared__ float sWm[64 * 64];
  __shared__ float sWu[64 * 64];  // top half of Wu (rows 0..63)
  const int tid = threadIdx.x;
  for (int i = tid; i < 4096; i += 256) {
    sWm[i] = Wm[i];
    sWu[i] = Wu[i];
  }
  __syncthreads();
  for (int i = tid; i < 4096; i += 256) {
    const int r = i >> 6, c = i & 63;
    float acc = 0.f;
#pragma unroll
    for (int k = 0; k < 64; ++k) acc = fmaf(sWm[r * 64 + k], sWu[k * 64 + c], acc);
    W1l[i] = acc;
  }
  if (tid < 64) {
    float acc = 0.f;
#pragma unroll
    for (int k = 0; k < 64; ++k) acc = fmaf(bm[k], sWu[k * 64 + tid], acc);
    dvl[tid] = acc;
  }
}

__global__ __launch_bounds__(256) void deg_kernel(const int* __restrict__ dst,
                                                  int* __restrict__ deg, int E) {
  const int e = blockIdx.x * 256 + threadIdx.x;
  if (e < E) atomicAdd(&deg[dst[e]], 1);
}

__global__ __launch_bounds__(1024) void scan_kernel(const int* __restrict__ deg,
                                                    int* __restrict__ rowptr, int n) {
  __shared__ int part[1024];
  const int t = threadIdx.x;
  const int chunk = (n + 1023) / 1024;
  const int b = t * chunk;
  const int e = min(n, b + chunk);
  int s = 0;
  for (int i = b; i < e; ++i) s += deg[i];
  part[t] = s;
  __syncthreads();
  for (int off = 1; off < 1024; off <<= 1) {
    int v = (t >= off) ? part[t - off] : 0;
    __syncthreads();
    part[t] += v;
    __syncthreads();
  }
  int run = (t == 0) ? 0 : part[t - 1];
  for (int i = b; i < e; ++i) {
    rowptr[i] = run;
    run += deg[i];
  }
  if (t == 1023) rowptr[n] = part[1023];
}

__global__ __launch_bounds__(256) void fill_kernel(
    const int* __restrict__ src, const int* __restrict__ dst,
    const int* __restrict__ rowptr, int* __restrict__ cursor,
    int* __restrict__ csr_src, int E) {
  const int e = blockIdx.x * 256 + threadIdx.x;
  if (e < E) {
    const int d = dst[e];
    const int p = atomicAdd(&cursor[d], 1);
    csr_src[rowptr[d] + p] = src[e];
  }
}

// One wave per node: aggregate into registers, then the update GEMM row via
// readlane broadcasts against register-resident weight columns.
__global__ __launch_bounds__(256) void layer_kernel(
    const float* __restrict__ x, const int* __restrict__ rowptr,
    const int* __restrict__ csr_src, const float* __restrict__ W1g,
    const float* __restrict__ Wu, const float* __restrict__ bu,
    const float* __restrict__ dvec, float* __restrict__ out, int n) {
  const int lane = threadIdx.x & 63;
  const int wid = (blockIdx.x * 256 + threadIdx.x) >> 6;
  const int nwaves = (gridDim.x * 256) >> 6;

  // Per-lane weight columns (static indexing only -> registers).
  float w1[64], w2[64];
#pragma unroll
  for (int k = 0; k < 64; ++k) w1[k] = W1g[k * 64 + lane];
#pragma unroll
  for (int k = 0; k < 64; ++k) w2[k] = Wu[(64 + k) * 64 + lane];
  const float bl = bu[lane];
  const float dl = dvec[lane];

  for (int node = wid; node < n; node += nwaves) {
    const int beg = rowptr[node];
    const int end = rowptr[node + 1];
    const int cnt = end - beg;
    const float xv = x[(size_t)node * 64 + lane];

    // Coalesced index prefetch: lane l holds csr_src[beg+l].
    int myi = 0;
    if (lane < cnt) myi = csr_src[beg + lane];
    const int c64 = cnt > 64 ? 64 : cnt;
    float h0 = 0.f, h1 = 0.f, h2 = 0.f, h3 = 0.f;
    int i = 0;
    for (; i + 3 < c64; i += 4) {
      const int s0 = __builtin_amdgcn_readlane(myi, i);
      const int s1 = __builtin_amdgcn_readlane(myi, i + 1);
      const int s2 = __builtin_amdgcn_readlane(myi, i + 2);
      const int s3 = __builtin_amdgcn_readlane(myi, i + 3);
      h0 += x[(size_t)s0 * 64 + lane];
      h1 += x[(size_t)s1 * 64 + lane];
      h2 += x[(size_t)s2 * 64 + lane];
      h3 += x[(size_t)s3 * 64 + lane];
    }
    for (; i < c64; ++i) {
      const int s = __builtin_amdgcn_readlane(myi, i);
      h0 += x[(size_t)s * 64 + lane];
    }
    for (int j = beg + 64; j < end; ++j)  // Poisson(16) tail: ~never taken
      h1 += x[(size_t)csr_src[j] * 64 + lane];
    const float hv = xv + (h0 + h1) + (h2 + h3);

    // Update GEMM row: acc = bu + (deg+1)*dvec + hv@W1 + xv@W2
    float acc_h = fmaf((float)(cnt + 1), dl, bl);
    float acc_x = 0.f;
#pragma unroll
    for (int k = 0; k < 64; ++k) {
      const float h_k = __uint_as_float(
          __builtin_amdgcn_readlane(__float_as_uint(hv), k));
      const float x_k = __uint_as_float(
          __builtin_amdgcn_readlane(__float_as_uint(xv), k));
      acc_h = fmaf(h_k, w1[k], acc_h);
      acc_x = fmaf(x_k, w2[k], acc_x);
    }
    const float v = acc_h + acc_x;
    out[(size_t)node * 64 + lane] = v > 0.f ? v : 0.f;
  }
}

extern "C" void kernel_launch(void* const* d_in, const int* in_sizes, int n_in,
                              void* d_out, int out_size, void* d_ws, size_t ws_size,
                              hipStream_t stream) {
  const float* x = (const float*)d_in[0];
  const int* ei = (const int*)d_in[1];
  const int n = in_sizes[0] / DIM;   // 50000
  const int E = in_sizes[1] / 2;     // 800000
  const int* srcp = ei;
  const int* dstp = ei + E;

  // Workspace layout:
  float* y1 = (float*)d_ws;                    // n*64 floats (layer-1 output)
  int* deg = (int*)(y1 + (size_t)n * DIM);     // n
  int* rowptr = deg + n;                       // n+1
  int* cursor = rowptr + n + 1;                // n
  int* csr_src = cursor + n;                   // E
  float* W1 = (float*)(csr_src + E);           // 3*4096
  float* dv = W1 + 3 * 4096;                   // 3*64

  // One-time prep: fused weights + CSR build.
  fuse_weights_kernel<<<3, 256, 0, stream>>>(
      (const float*)d_in[2], (const float*)d_in[3], (const float*)d_in[4],
      (const float*)d_in[6], (const float*)d_in[7], (const float*)d_in[8],
      (const float*)d_in[10], (const float*)d_in[11], (const float*)d_in[12],
      W1, dv);
  hipMemsetAsync(deg, 0, (size_t)n * sizeof(int), stream);
  hipMemsetAsync(cursor, 0, (size_t)n * sizeof(int), stream);
  deg_kernel<<<(E + 255) / 256, 256, 0, stream>>>(dstp, deg, E);
  scan_kernel<<<1, 1024, 0, stream>>>(deg, rowptr, n);
  fill_kernel<<<(E + 255) / 256, 256, 0, stream>>>(srcp, dstp, rowptr, cursor, csr_src, E);

  // Layer chain: x -> d_out -> y1 -> d_out
  float* outs[3] = {(float*)d_out, y1, (float*)d_out};
  const float* xin = x;
  for (int l = 0; l < 3; ++l) {
    layer_kernel<<<1024, 256, 0, stream>>>(
        xin, rowptr, csr_src, W1 + l * 4096, (const float*)d_in[4 + 4 * l],
        (const float*)d_in[5 + 4 * l], dv + l * 64, outs[l], n);
    xin = outs[l];
  }
}